// Round 4
// baseline (1505.057 us; speedup 1.0000x reference)
//
#include <hip/hip_runtime.h>

typedef __bf16 bf16_t;
typedef __bf16 bf16x4 __attribute__((ext_vector_type(4)));
typedef __bf16 bf16x8 __attribute__((ext_vector_type(8)));
typedef float f32x4 __attribute__((ext_vector_type(4)));

#define GLL16(gp, lp) __builtin_amdgcn_global_load_lds( \
    (__attribute__((address_space(1))) void*)(gp),      \
    (__attribute__((address_space(3))) void*)(lp), 16, 0, 0)

// ---------------------------------------------------------------------------
// 256x256-tile software-pipelined GEMM.
//   C[half][M,N] = epi(A[half][M,K] @ W[half][N,K]^T + bias[half])
// 512 threads = 8 waves (2M x 4N); per-wave output 128x64. BK=64.
// LDS 128 KiB (2 dbuf x (A 256x64 + B 256x64) bf16), 16B-granule XOR swizzle
// by row&7 on both global source and ds_read (rule 21 both-sides).
// Phase map per K-tile: (kk, m-half) = (0,lo),(0,hi),(1,lo),(1,hi).
// Phase p ISSUES ds_reads for phase p+1 (4 af + optionally 4 bq), then
// barrier, then MFMA(p) — compiler emits counted lgkm waits, so read latency
// hides under the previous MFMA cluster. Frag banks ping-pong per phase
// (afA/afB, bqA/bqB: 16 VGPR each) -> total regs ~235 < 256 (2 waves/SIMD).
// Stage-all 8 global_load_lds at ph0 -> vmcnt(0) at ph3 (~3 phases slack);
// next-tile ph0 frags read at ph3 after the stage-sync barrier.
// Epilogue: n-innermost store order (full-line write combining).
// Block remap: XCD owns 8 byh rows x all c, in 8x4 windows (L2 reuse).
// EPI: 0 relu->bf16, 1 bias->bf16, 2 sigmoid(U)*v->bf16, 3 bias->f32
// ---------------------------------------------------------------------------
#define STAGE_ALL(NXT) do {                                                  \
    _Pragma("unroll") for (int r = 0; r < 4; ++r)                            \
        GLL16(aub[r] + koff + voffA, &As[NXT][(r * 512 + w * 64) * 8]);      \
    _Pragma("unroll") for (int r = 0; r < 4; ++r)                            \
        GLL16(bub[r] + koff + voffB, &Bs[NXT][(r * 512 + w * 64) * 8]);      \
    koff += 64; } while (0)

#define AF_READ(TP, mh, kk, DST)                                             \
    _Pragma("unroll") for (int mm = 0; mm < 4; ++mm)                         \
        DST[mm] = *(const bf16x8*)(aT##TP + ((mh) * 4 + mm) * 1024 +         \
                                   (g0 ^ ((kk) << 2)) * 8);

#define BQ_READ(TP, kk, DST)                                                 \
    _Pragma("unroll") for (int n = 0; n < 4; ++n)                            \
        DST[n] = *(const bf16x8*)(bT##TP + n * 1024 +                        \
                                  (g0 ^ ((kk) << 2)) * 8);

#define MFMA_PH(mh, AF, BQ)                                                  \
    __builtin_amdgcn_s_setprio(1);                                           \
    _Pragma("unroll") for (int mm = 0; mm < 4; ++mm)                         \
    _Pragma("unroll") for (int n = 0; n < 4; ++n)                            \
        acc[(mh) * 4 + mm][n] = __builtin_amdgcn_mfma_f32_16x16x32_bf16(     \
            AF[mm], BQ[n], acc[(mh) * 4 + mm][n], 0, 0, 0);                  \
    __builtin_amdgcn_s_setprio(0);

#define TILE(CUR, NXT, doStage, doNext) do {                                 \
    /* ph0: compute (kk0,m0-3) w/ afA,bqA; prefetch afB<-(m4-7,kk0) */       \
    if (doStage) { STAGE_ALL(NXT); }                                         \
    AF_READ(CUR, 1, 0, afB);                                                 \
    __builtin_amdgcn_s_barrier();                                            \
    MFMA_PH(0, afA, bqA);                                                    \
    __builtin_amdgcn_s_barrier();                                            \
    /* ph1: (kk0,m4-7) w/ afB,bqA; prefetch afA<-(m0-3,kk1), bqB<-(kk1) */   \
    AF_READ(CUR, 0, 1, afA);                                                 \
    BQ_READ(CUR, 1, bqB);                                                    \
    __builtin_amdgcn_s_barrier();                                            \
    MFMA_PH(1, afB, bqA);                                                    \
    __builtin_amdgcn_s_barrier();                                            \
    /* ph2: (kk1,m0-3) w/ afA,bqB; prefetch afB<-(m4-7,kk1) */               \
    AF_READ(CUR, 1, 1, afB);                                                 \
    __builtin_amdgcn_s_barrier();                                            \
    MFMA_PH(0, afA, bqB);                                                    \
    __builtin_amdgcn_s_barrier();                                            \
    /* ph3: (kk1,m4-7) w/ afB,bqB; stage-sync then prefetch t+1 ph0 */       \
    if (doStage) { asm volatile("s_waitcnt vmcnt(0)" ::: "memory"); }        \
    __builtin_amdgcn_s_barrier();                                            \
    if (doNext) { AF_READ(NXT, 0, 0, afA); BQ_READ(NXT, 0, bqA); }           \
    MFMA_PH(1, afB, bqB);                                                    \
    __builtin_amdgcn_s_barrier();                                            \
    } while (0)

template<int EPI>
__global__ __launch_bounds__(512, 2)
void gemm256(const bf16_t* __restrict__ A0, const bf16_t* __restrict__ A1, int lda,
             const bf16_t* __restrict__ W0, const bf16_t* __restrict__ W1,
             const float* __restrict__ bias0, const float* __restrict__ bias1,
             const bf16_t* __restrict__ U0, const bf16_t* __restrict__ U1,
             void* __restrict__ C0v, void* __restrict__ C1v, int ldc,
             int K, int nbx, int nbyH)
{
    __shared__ bf16_t As[2][16384];
    __shared__ bf16_t Bs[2][16384];

    const int t = threadIdx.x;
    const int w = t >> 6, l = t & 63;
    const int wr = w >> 2, wc = w & 3;        // 2 x 4 wave grid
    const int ro = l & 15, hi = l >> 4;
    const int g0 = hi ^ (ro & 7);             // swizzled granule, kk=0

    // XCD-window remap (gridDim%8==0, nbyH%8==0, c_total%4==0):
    const int xcd   = blockIdx.x & 7;
    const int local = blockIdx.x >> 3;
    const int cg    = local >> 5;
    const int r5    = local & 31;
    const int byh   = xcd * (nbyH >> 3) + (r5 >> 2);
    const int c     = cg * 4 + (r5 & 3);
    const int sel   = (c >= nbx) ? 1 : 0;
    const int bx    = c - sel * nbx;

    const bf16_t* A    = sel ? A1 : A0;
    const bf16_t* W    = sel ? W1 : W0;
    const float*  bias = sel ? bias1 : bias0;
    const bf16_t* Up   = sel ? U1 : U0;
    void*         Cp   = sel ? C1v : C0v;

    const bf16_t* Ab = A + (size_t)byh * 256 * lda;
    const bf16_t* Wb = W + (size_t)bx * 256 * K;

    // uniform per-r bases (SGPR) + per-lane swizzled offset (VGPR)
    const int rr   = t >> 3;                   // staging row within 64-group
    const int cswz = (t & 7) ^ (rr & 7);       // inverse of ds_read swizzle
    const int voffA = rr * lda + cswz * 8;
    const int voffB = rr * K   + cswz * 8;
    const bf16_t* aub[4];
    const bf16_t* bub[4];
#pragma unroll
    for (int r = 0; r < 4; ++r) {
        aub[r] = Ab + (size_t)(r * 64) * lda;
        bub[r] = Wb + (size_t)(r * 64) * K;
    }
    int koff = 0;

    const bf16_t* aT0 = &As[0][(wr * 128 + ro) * 64];
    const bf16_t* aT1 = &As[1][(wr * 128 + ro) * 64];
    const bf16_t* bT0 = &Bs[0][(wc * 64 + ro) * 64];
    const bf16_t* bT1 = &Bs[1][(wc * 64 + ro) * 64];

    f32x4 acc[8][4] = {};
    bf16x8 afA[4], afB[4], bqA[4], bqB[4];

    // prologue: stage tile 0 into buf0, drain, read ph0 frags
    STAGE_ALL(0);
    asm volatile("s_waitcnt vmcnt(0)" ::: "memory");
    __builtin_amdgcn_s_barrier();
    AF_READ(0, 0, 0, afA);
    BQ_READ(0, 0, bqA);

    const int NT = K >> 6;                    // K-tiles (even)
    for (int tp = 0; tp < NT; tp += 2) {
        TILE(0, 1, true, true);
        const bool more = (tp + 2 < NT);
        TILE(1, 0, more, more);
    }

    // epilogue: C/D frag layout col=lane&15, row=(lane>>4)*4+j  [guide m89]
    // n-innermost: each 128B line gets its 4x32B stores back-to-back.
    const int rbase = byh * 256 + wr * 128 + (hi << 2);
    const int cbase = bx * 256 + wc * 64 + ro;
    float bc[4];
#pragma unroll
    for (int n = 0; n < 4; ++n) bc[n] = bias[cbase + n * 16];
#pragma unroll
    for (int m = 0; m < 8; ++m) {
#pragma unroll
        for (int j = 0; j < 4; ++j) {
            const int row = rbase + m * 16 + j;
            const size_t off = (size_t)row * ldc + cbase;
#pragma unroll
            for (int n = 0; n < 4; ++n) {
                float v = acc[m][n][j] + bc[n];
                if (EPI == 0) v = fmaxf(v, 0.0f);
                if (EPI == 2) {
                    const float u = (float)Up[off + n * 16];
                    v *= 1.0f / (1.0f + __expf(-u));
                }
                if (EPI == 3) ((float*)Cp)[off + n * 16] = v;
                else          ((bf16_t*)Cp)[off + n * 16] = (bf16_t)v;
            }
        }
    }
}

// ---------------------------------------------------------------------------
struct WSrcs { const float* p[10]; };

__global__ __launch_bounds__(256)
void cast_weights(WSrcs srcs, bf16_t* __restrict__ dst)
{
    const int region = blockIdx.x >> 10;
    const float* src = srcs.p[region];
    const size_t base = (size_t)(blockIdx.x & 1023) * 1024 + threadIdx.x * 4;
    const float4 f = *(const float4*)(src + base);
    bf16x4 h = {(bf16_t)f.x, (bf16_t)f.y, (bf16_t)f.z, (bf16_t)f.w};
    *(bf16x4*)(dst + ((size_t)region << 20) + base) = h;
}

__global__ __launch_bounds__(256)
void cast_act(const float* __restrict__ src, bf16_t* __restrict__ dst)
{
    const size_t i = ((size_t)blockIdx.x * 256 + threadIdx.x) * 4;
    const float4 f = *(const float4*)(src + i);
    bf16x4 h = {(bf16_t)f.x, (bf16_t)f.y, (bf16_t)f.z, (bf16_t)f.w};
    *(bf16x4*)(dst + i) = h;
}

__global__ __launch_bounds__(256)
void concat_bias(const float* __restrict__ a, const float* __restrict__ b,
                 float* __restrict__ dst)
{
    const int i = blockIdx.x * 256 + threadIdx.x;
    if (i < 1024) dst[i] = a[i];
    else if (i < 2048) dst[i] = b[i - 1024];
}

// ---------------------------------------------------------------------------
// One block per row: dual l2norm + sigmoid gate + exact top-80 (radix select
// on abs bits, stable lowest-index tie-break) + sparse write + visual concat.
// ---------------------------------------------------------------------------
__global__ __launch_bounds__(256)
void finalize_topk(float* __restrict__ AgF,      // OUT2: in Ag, out final
                   float* __restrict__ AlF,      // OUT3: in Al, out f2
                   const float* __restrict__ VIS,
                   float* __restrict__ O1)
{
    const int row = blockIdx.x, t = threadIdx.x;
    __shared__ int bins[256];
    __shared__ int sscan[256];
    __shared__ float wred[8];
    __shared__ int s_sel, s_kk;

    float* agp = AgF + (size_t)row * 1024 + t * 4;
    float* alp = AlF + (size_t)row * 1024 + t * 4;
    const float4 a4 = *(const float4*)agp;
    const float4 l4 = *(const float4*)alp;
    float av[4] = {a4.x, a4.y, a4.z, a4.w};
    float lv[4] = {l4.x, l4.y, l4.z, l4.w};
    float sa = 0.0f, sb = 0.0f;
#pragma unroll
    for (int j = 0; j < 4; ++j) { sa += av[j] * av[j]; sb += lv[j] * lv[j]; }
#pragma unroll
    for (int o = 32; o > 0; o >>= 1) {
        sa += __shfl_down(sa, o);
        sb += __shfl_down(sb, o);
    }
    if ((t & 63) == 0) { wred[t >> 6] = sa; wred[4 + (t >> 6)] = sb; }
    __syncthreads();
    const float sca = 1.0f / fmaxf(sqrtf(wred[0] + wred[1] + wred[2] + wred[3]), 1e-12f);
    const float scl = 1.0f / fmaxf(sqrtf(wred[4] + wred[5] + wred[6] + wred[7]), 1e-12f);

    float fv[4], f2v[4];
    unsigned ab[4];
#pragma unroll
    for (int j = 0; j < 4; ++j) {
        const float f2 = lv[j] * scl;
        const float f1 = av[j] * sca;
        const float fin = f2 / (1.0f + __expf(-f1));   // sigmoid(f1)*f2
        f2v[j] = f2; fv[j] = fin;
        ab[j] = __float_as_uint(fin) & 0x7fffffffu;
    }
    *(float4*)alp = make_float4(f2v[0], f2v[1], f2v[2], f2v[3]);
    *(float4*)agp = make_float4(fv[0], fv[1], fv[2], fv[3]);

    const float* vr = VIS + (size_t)row * 2048;
    float* o1r = O1 + (size_t)row * 3072;
    *(float4*)(o1r + t * 4)        = *(const float4*)(vr + t * 4);
    *(float4*)(o1r + 1024 + t * 4) = *(const float4*)(vr + 1024 + t * 4);

    // --- radix select: exact bits of the 80th-largest |fin| ---
    unsigned pref = 0u, msk = 0u;
    int kk = 80;
    for (int bp = 3; bp >= 0; --bp) {
        bins[t] = 0;
        __syncthreads();
#pragma unroll
        for (int j = 0; j < 4; ++j)
            if ((ab[j] & msk) == pref)
                atomicAdd(&bins[(ab[j] >> (bp * 8)) & 255], 1);
        __syncthreads();
        sscan[t] = bins[t];
        __syncthreads();
        for (int o = 1; o < 256; o <<= 1) {           // suffix sum
            const int add = (t + o < 256) ? sscan[t + o] : 0;
            __syncthreads();
            sscan[t] += add;
            __syncthreads();
        }
        const int Sme = sscan[t];
        const int Snx = (t < 255) ? sscan[t + 1] : 0;
        if (Sme >= kk && Snx < kk) { s_sel = t; s_kk = kk - Snx; }
        __syncthreads();
        pref |= (unsigned)s_sel << (bp * 8);
        msk  |= 0xFFu << (bp * 8);
        kk = s_kk;
        __syncthreads();
    }

    // stable tie-break: keep first kk elements equal to threshold (index order)
    int ec = 0;
#pragma unroll
    for (int j = 0; j < 4; ++j) ec += (ab[j] == pref) ? 1 : 0;
    sscan[t] = ec;
    __syncthreads();
    for (int o = 1; o < 256; o <<= 1) {               // inclusive prefix sum
        const int add = (t >= o) ? sscan[t - o] : 0;
        __syncthreads();
        sscan[t] += add;
        __syncthreads();
    }
    int excl = sscan[t] - ec;
#pragma unroll
    for (int j = 0; j < 4; ++j) {
        const bool eq = (ab[j] == pref);
        const bool kp = (ab[j] > pref) || (eq && (excl < kk));
        o1r[2048 + t * 4 + j] = kp ? fv[j] : 0.0f;
        if (eq) ++excl;
    }
}

// ---------------------------------------------------------------------------
extern "C" void kernel_launch(void* const* d_in, const int* in_sizes, int n_in,
                              void* d_out, int out_size, void* d_ws, size_t ws_size,
                              hipStream_t stream)
{
    const float* SG   = (const float*)d_in[0];
    const float* SL   = (const float*)d_in[1];
    const float* VIS  = (const float*)d_in[2];
    const float* Wgu1 = (const float*)d_in[3];
    const float* bgu1 = (const float*)d_in[4];
    const float* Wgu2 = (const float*)d_in[5];  const float* bgu2 = (const float*)d_in[6];
    const float* Wgd1 = (const float*)d_in[7];  const float* bgd1 = (const float*)d_in[8];
    const float* Wgd2 = (const float*)d_in[9];  const float* bgd2 = (const float*)d_in[10];
    const float* Wlu1 = (const float*)d_in[11]; const float* blu1 = (const float*)d_in[12];
    const float* Wlu2 = (const float*)d_in[13]; const float* blu2 = (const float*)d_in[14];
    const float* Wld1 = (const float*)d_in[15]; const float* bld1 = (const float*)d_in[16];
    const float* Wld2 = (const float*)d_in[17]; const float* bld2 = (const float*)d_in[18];
    const float* Wo   = (const float*)d_in[19]; const float* bo   = (const float*)d_in[20];
    const float* Win  = (const float*)d_in[21]; const float* bin_ = (const float*)d_in[22];
    const float* Wv = Win + (size_t)2 * 1024 * 1024;   // Win[2E:]
    const float* bv = bin_ + 2048;

    float* OUT1 = (float*)d_out;                         // B x 3072
    float* OUT2 = OUT1 + (size_t)16384 * 3072;           // B x 1024 (final)
    float* OUT3 = OUT2 + (size_t)16384 * 1024;           // B x 1024 (f2)

    // ws: bf16 weights + concat'd biases
    char* ws = (char*)d_ws;
    bf16_t* Wbf = (bf16_t*)ws;                           // 10M bf16
    float*  bb  = (float*)(ws + 20971520);               // 4096 f32

    // scratch inside d_out (320 MiB total), lifetime-checked (see r2 notes)
    bf16_t* X   = (bf16_t*)d_out;
    bf16_t* Y   = X + (size_t)16384 * 1024;
    bf16_t* Ug  = (bf16_t*)((char*)d_out + 67108864);
    bf16_t* Ul  = (bf16_t*)((char*)d_out + 100663296);
    bf16_t* V   = (bf16_t*)((char*)d_out + 67108864);
    bf16_t* V2  = V + (size_t)16384 * 1024;
    bf16_t* H1g = (bf16_t*)((char*)d_out + 134217728);
    bf16_t* H1l = (bf16_t*)((char*)d_out + 201326592);

    WSrcs srcs;
    srcs.p[0] = Wgu1; srcs.p[1] = Wgd1; srcs.p[2] = Wlu1; srcs.p[3] = Wld1;
    srcs.p[4] = Wgu2; srcs.p[5] = Wgd2; srcs.p[6] = Wlu2; srcs.p[7] = Wld2;
    srcs.p[8] = Wv;   srcs.p[9] = Wo;

    cast_weights<<<10240, 256, 0, stream>>>(srcs, Wbf);
    concat_bias<<<8, 256, 0, stream>>>(bgu1, bgd1, bb);
    concat_bias<<<8, 256, 0, stream>>>(blu1, bld1, bb + 2048);
    cast_act<<<16384, 256, 0, stream>>>(SG, X);
    cast_act<<<16384, 256, 0, stream>>>(SL, Y);

    bf16_t* Wg1   = Wbf;                                 // [Wgu1;Wgd1] 2048x1024
    bf16_t* Wl1   = Wbf + (size_t)2 * 1048576;           // [Wlu1;Wld1]
    bf16_t* Wgu2b = Wbf + (size_t)4 * 1048576;
    bf16_t* Wgd2b = Wbf + (size_t)5 * 1048576;
    bf16_t* Wlu2b = Wbf + (size_t)6 * 1048576;
    bf16_t* Wld2b = Wbf + (size_t)7 * 1048576;
    bf16_t* Wvb   = Wbf + (size_t)8 * 1048576;
    bf16_t* Wob   = Wbf + (size_t)9 * 1048576;

    // D1: h1 = relu([X;Y] @ [W?u1;W?d1]^T + b), per-half weights. N=2048.
    gemm256<0><<<1024, 512, 0, stream>>>(X, Y, 1024, Wg1, Wl1, bb, bb + 2048,
                                         nullptr, nullptr, H1g, H1l, 2048, 1024, 8, 64);
    // D2: U = h1[:, :1024] @ W?u2^T + b  (gate pre-act)
    gemm256<1><<<512, 512, 0, stream>>>(H1g, H1l, 2048, Wgu2b, Wlu2b, bgu2, blu2,
                                        nullptr, nullptr, Ug, Ul, 1024, 1024, 4, 64);
    // D3: s? = sigmoid(U) * (h1[:, 1024:] @ W?d2^T + b)  -> X, Y
    gemm256<2><<<512, 512, 0, stream>>>(H1g + 1024, H1l + 1024, 2048, Wgd2b, Wld2b,
                                        bgd2, bld2, Ug, Ul, X, Y, 1024, 1024, 4, 64);
    // D4: V = [sg;sl] @ Wv^T + bv
    gemm256<1><<<512, 512, 0, stream>>>(X, Y, 1024, Wvb, Wvb, bv, bv,
                                        nullptr, nullptr, V, V2, 1024, 1024, 4, 64);
    // D5: pre-norm attn_out = V @ Wo^T + bo  -> OUT2 (sg rows), OUT3 (sl rows)
    gemm256<3><<<512, 512, 0, stream>>>(V, V2, 1024, Wob, Wob, bo, bo,
                                        nullptr, nullptr, OUT2, OUT3, 1024, 1024, 4, 64);

    finalize_topk<<<16384, 256, 0, stream>>>(OUT2, OUT3, VIS, OUT1);
}

// Round 5
// 673.871 us; speedup vs baseline: 2.2335x; 2.2335x over previous
//
#include <hip/hip_runtime.h>

typedef __bf16 bf16_t;
typedef __bf16 bf16x4 __attribute__((ext_vector_type(4)));
typedef __bf16 bf16x8 __attribute__((ext_vector_type(8)));
typedef float f32x4 __attribute__((ext_vector_type(4)));

#define GLL16(gp, lp) __builtin_amdgcn_global_load_lds( \
    (__attribute__((address_space(1))) void*)(gp),      \
    (__attribute__((address_space(3))) void*)(lp), 16, 0, 0)

// ---------------------------------------------------------------------------
// 256x256-tile 4-phase/K-tile GEMM (r3 structure, verified 697 TF here).
//   C[half][M,N] = epi(A[half][M,K] @ W[half][N,K]^T + bias[half])
// 512 threads = 8 waves (2M x 4N); per-wave output 128x64. BK=64.
// LDS 128 KiB (2 dbuf x (A 256x64 + B 256x64) bf16).
// 16B-granule XOR swizzle (row&7) on both global source and ds_read.
// Stage-all 8 global_load_lds at ph0; vmcnt(0) at ph3 (~3 phases slack).
// Per phase: barrier -> lgkmcnt(0) -> sched_barrier -> setprio(1) -> 16 MFMA.
// Epilogue n-innermost (full-line write combining).
// XCD window remap: XCD owns nbyH/8 byh rows x all c, iterated in 8x4
// (byh x c) windows -> A panel + W slice concurrently L2-resident.
// EPI: 0 relu->bf16, 1 bias->bf16, 2 sigmoid(U)*v->bf16, 3 bias->f32
// ---------------------------------------------------------------------------
#define STAGE_ALL(NXT) do {                                                  \
    _Pragma("unroll") for (int r = 0; r < 4; ++r) {                          \
        GLL16(asrc[r], &As[NXT][(r * 512 + w * 64) * 8]);                    \
        asrc[r] += 64;                                                       \
    }                                                                        \
    _Pragma("unroll") for (int r = 0; r < 4; ++r) {                          \
        GLL16(bsrc[r], &Bs[NXT][(r * 512 + w * 64) * 8]);                    \
        bsrc[r] += 64;                                                       \
    } } while (0)

#define LOADA(CUR, m0) do {                                                  \
    _Pragma("unroll") for (int mm = 0; mm < 2; ++mm)                         \
    _Pragma("unroll") for (int kk = 0; kk < 2; ++kk)                         \
        af[mm][kk] = *(const bf16x8*)(aT##CUR + ((m0) + mm) * 1024 +         \
                                      (g0 ^ (kk << 2)) * 8);                 \
    } while (0)

#define PHASE_MFMA(m0)                                                       \
    __builtin_amdgcn_s_barrier();                                            \
    asm volatile("s_waitcnt lgkmcnt(0)" ::: "memory");                       \
    __builtin_amdgcn_sched_barrier(0);                                       \
    __builtin_amdgcn_s_setprio(1);                                           \
    _Pragma("unroll") for (int mm = 0; mm < 2; ++mm)                         \
    _Pragma("unroll") for (int n = 0; n < 4; ++n)                            \
    _Pragma("unroll") for (int kk = 0; kk < 2; ++kk)                         \
        acc[(m0) + mm][n] = __builtin_amdgcn_mfma_f32_16x16x32_bf16(         \
            af[mm][kk], bq[n][kk], acc[(m0) + mm][n], 0, 0, 0);              \
    __builtin_amdgcn_s_setprio(0);

#define ITER(CUR, NXT, doStage) do {                                         \
    if (doStage) { STAGE_ALL(NXT); }                                         \
    _Pragma("unroll") for (int n = 0; n < 4; ++n)                            \
    _Pragma("unroll") for (int kk = 0; kk < 2; ++kk)                         \
        bq[n][kk] = *(const bf16x8*)(bT##CUR + n * 1024 +                    \
                                     (g0 ^ (kk << 2)) * 8);                  \
    LOADA(CUR, 0);                                                           \
    PHASE_MFMA(0);                                                           \
    __builtin_amdgcn_s_barrier();                                            \
    LOADA(CUR, 2);                                                           \
    PHASE_MFMA(2);                                                           \
    __builtin_amdgcn_s_barrier();                                            \
    LOADA(CUR, 4);                                                           \
    PHASE_MFMA(4);                                                           \
    __builtin_amdgcn_s_barrier();                                            \
    LOADA(CUR, 6);                                                           \
    PHASE_MFMA(6);                                                           \
    asm volatile("s_waitcnt vmcnt(0)" ::: "memory");                         \
    __builtin_amdgcn_s_barrier();                                            \
    } while (0)

template<int EPI>
__global__ __launch_bounds__(512, 2)
void gemm256(const bf16_t* __restrict__ A0, const bf16_t* __restrict__ A1, int lda,
             const bf16_t* __restrict__ W0, const bf16_t* __restrict__ W1,
             const float* __restrict__ bias0, const float* __restrict__ bias1,
             const bf16_t* __restrict__ U0, const bf16_t* __restrict__ U1,
             void* __restrict__ C0v, void* __restrict__ C1v, int ldc,
             int K, int nbx, int nbyH, int ctot)
{
    __shared__ bf16_t As[2][16384];
    __shared__ bf16_t Bs[2][16384];

    const int t = threadIdx.x;
    const int w = t >> 6, l = t & 63;
    const int wr = w >> 2, wc = w & 3;        // 2 x 4 wave grid
    const int ro = l & 15, hi = l >> 4;
    const int g0 = hi ^ (ro & 7);             // swizzled granule, kk=0

    // XCD-window remap (gridDim%8==0, nbyH%8==0, ctot%4==0):
    // XCD owns nbyH/8 byh rows; iterate in 8-byh x 4-c windows.
    const int xcd   = blockIdx.x & 7;
    const int local = blockIdx.x >> 3;
    const int wpb   = ctot >> 2;              // c-windows per byh stripe
    const int win   = local >> 5;
    const int r5    = local & 31;
    const int strp  = win / wpb;
    const int wcn   = win - strp * wpb;
    const int byh   = xcd * (nbyH >> 3) + strp * 8 + (r5 >> 2);
    const int c     = wcn * 4 + (r5 & 3);
    const int sel   = (c >= nbx) ? 1 : 0;
    const int bx    = c - sel * nbx;

    const bf16_t* A    = sel ? A1 : A0;
    const bf16_t* W    = sel ? W1 : W0;
    const float*  bias = sel ? bias1 : bias0;
    const bf16_t* Up   = sel ? U1 : U0;
    void*         Cp   = sel ? C1v : C0v;

    const bf16_t* Ab = A + (size_t)byh * 256 * lda;
    const bf16_t* Wb = W + (size_t)bx * 256 * K;

    // pre-swizzled per-lane global sources (inverse of the ds_read swizzle)
    const bf16_t* asrc[4];
    const bf16_t* bsrc[4];
#pragma unroll
    for (int r = 0; r < 4; ++r) {
        const int g   = r * 512 + t;          // 16B granule id in 256x64 tile
        const int row = g >> 3;
        const int cgr = (g & 7) ^ (row & 7);
        asrc[r] = Ab + (size_t)row * lda + cgr * 8;
        bsrc[r] = Wb + (size_t)row * K   + cgr * 8;
    }

    const bf16_t* aT0 = &As[0][(wr * 128 + ro) * 64];
    const bf16_t* aT1 = &As[1][(wr * 128 + ro) * 64];
    const bf16_t* bT0 = &Bs[0][(wc * 64 + ro) * 64];
    const bf16_t* bT1 = &Bs[1][(wc * 64 + ro) * 64];

    f32x4 acc[8][4] = {};
    bf16x8 bq[4][2];
    bf16x8 af[2][2];

    // prologue: stage tile 0 into buf0, full drain once
    STAGE_ALL(0);
    asm volatile("s_waitcnt vmcnt(0)" ::: "memory");
    __builtin_amdgcn_s_barrier();

    const int NT = K >> 6;                    // K-tiles (even)
    for (int tp = 0; tp < NT; tp += 2) {
        ITER(0, 1, true);
        ITER(1, 0, (tp + 2 < NT));
    }

    // epilogue: C/D frag layout col=lane&15, row=(lane>>4)*4+j  [guide m89]
    const int rbase = byh * 256 + wr * 128 + (hi << 2);
    const int cbase = bx * 256 + wc * 64 + ro;
    float bc[4];
#pragma unroll
    for (int n = 0; n < 4; ++n) bc[n] = bias[cbase + n * 16];
#pragma unroll
    for (int m = 0; m < 8; ++m) {
#pragma unroll
        for (int j = 0; j < 4; ++j) {
            const int row = rbase + m * 16 + j;
            const size_t off = (size_t)row * ldc + cbase;
#pragma unroll
            for (int n = 0; n < 4; ++n) {
                float v = acc[m][n][j] + bc[n];
                if (EPI == 0) v = fmaxf(v, 0.0f);
                if (EPI == 2) {
                    const float u = (float)Up[off + n * 16];
                    v *= 1.0f / (1.0f + __expf(-u));
                }
                if (EPI == 3) ((float*)Cp)[off + n * 16] = v;
                else          ((bf16_t*)Cp)[off + n * 16] = (bf16_t)v;
            }
        }
    }
}

// ---------------------------------------------------------------------------
// Small 128x128-tile GEMM (r1 structure) for the Wo@Wv weight compose.
// C[M,N](bf16) = A[M,K] @ W[N,K]^T, no bias. Grid (N/128, M/128).
// ---------------------------------------------------------------------------
__global__ __launch_bounds__(256, 2)
void gemm_small_bt(const bf16_t* __restrict__ A, int lda,
                   const bf16_t* __restrict__ W,
                   bf16_t* __restrict__ C, int ldc, int K)
{
    __shared__ bf16_t As[128 * 64];
    __shared__ bf16_t Bs[128 * 64];
    const int t = threadIdx.x;
    const int w = t >> 6, l = t & 63;
    const int wr = w >> 1, wc = w & 1;

    const bf16_t* Ab = A + (size_t)blockIdx.y * 128 * lda;
    const bf16_t* Wb = W + (size_t)blockIdx.x * 128 * K;

    const bf16_t* asrc[4];
    const bf16_t* bsrc[4];
#pragma unroll
    for (int r = 0; r < 4; ++r) {
        const int seg = r * 256 + t;
        asrc[r] = Ab + (size_t)(seg >> 3) * lda + (seg & 7) * 8;
        bsrc[r] = Wb + (size_t)(seg >> 3) * K   + (seg & 7) * 8;
    }

    f32x4 acc[4][4] = {};

    for (int kt = 0; kt < K; kt += 64) {
#pragma unroll
        for (int r = 0; r < 4; ++r) {
            GLL16(asrc[r], As + (r * 256 + w * 64) * 8);
            GLL16(bsrc[r], Bs + (r * 256 + w * 64) * 8);
            asrc[r] += 64;
            bsrc[r] += 64;
        }
        __syncthreads();
#pragma unroll
        for (int kk = 0; kk < 2; ++kk) {
            const int ro = l & 15;
            const int ko = kk * 32 + (l >> 4) * 8;
            bf16x8 af[4], bq[4];
#pragma unroll
            for (int m = 0; m < 4; ++m)
                af[m] = *(const bf16x8*)(As + (wr * 64 + m * 16 + ro) * 64 + ko);
#pragma unroll
            for (int n = 0; n < 4; ++n)
                bq[n] = *(const bf16x8*)(Bs + (wc * 64 + n * 16 + ro) * 64 + ko);
#pragma unroll
            for (int m = 0; m < 4; ++m)
#pragma unroll
                for (int n = 0; n < 4; ++n)
                    acc[m][n] = __builtin_amdgcn_mfma_f32_16x16x32_bf16(
                        af[m], bq[n], acc[m][n], 0, 0, 0);
        }
        __syncthreads();
    }

    const int rbase = blockIdx.y * 128 + wr * 64 + ((l >> 4) << 2);
    const int cbase = blockIdx.x * 128 + wc * 64 + (l & 15);
#pragma unroll
    for (int m = 0; m < 4; ++m)
#pragma unroll
        for (int j = 0; j < 4; ++j) {
            const int row = rbase + m * 16 + j;
#pragma unroll
            for (int n = 0; n < 4; ++n)
                C[(size_t)row * ldc + cbase + n * 16] = (bf16_t)acc[m][n][j];
        }
}

// ---------------------------------------------------------------------------
struct WSrcs { const float* p[9]; };

__global__ __launch_bounds__(256)
void cast_weights(WSrcs srcs, bf16_t* __restrict__ dst)
{
    const int region = blockIdx.x >> 10;
    const float* src = srcs.p[region];
    const size_t base = (size_t)(blockIdx.x & 1023) * 1024 + threadIdx.x * 4;
    const float4 f = *(const float4*)(src + base);
    bf16x4 h = {(bf16_t)f.x, (bf16_t)f.y, (bf16_t)f.z, (bf16_t)f.w};
    *(bf16x4*)(dst + ((size_t)region << 20) + base) = h;
}

// Wv[m][k] (f32) -> WvT[k][m] (bf16); 64x64 tiles via padded LDS.
__global__ __launch_bounds__(256)
void transpose_cast(const float* __restrict__ src, bf16_t* __restrict__ dst)
{
    __shared__ bf16_t tile[64][65];
    const int bm = blockIdx.y * 64, bk = blockIdx.x * 64;
    const int t = threadIdx.x;
#pragma unroll
    for (int s = 0; s < 4; ++s) {
        const int r = s * 16 + (t >> 4);
        const int c = (t & 15) * 4;
        const float4 f = *(const float4*)(src + (size_t)(bm + r) * 1024 + bk + c);
        tile[r][c] = (bf16_t)f.x; tile[r][c + 1] = (bf16_t)f.y;
        tile[r][c + 2] = (bf16_t)f.z; tile[r][c + 3] = (bf16_t)f.w;
    }
    __syncthreads();
#pragma unroll
    for (int s = 0; s < 4; ++s) {
        const int k = s * 16 + (t >> 4);
        const int m = (t & 15) * 4;
        bf16x4 v = {tile[m][k], tile[m + 1][k], tile[m + 2][k], tile[m + 3][k]};
        *(bf16x4*)(dst + (size_t)(bk + k) * 1024 + bm + m) = v;
    }
}

// bvo[j] = dot(Wo[j,:], bv) + bo[j]
__global__ __launch_bounds__(256)
void bias_compose(const float* __restrict__ Wo, const float* __restrict__ bv,
                  const float* __restrict__ bo, float* __restrict__ bvo)
{
    const int j = blockIdx.x, t = threadIdx.x;
    __shared__ float ws4[4];
    const float* wr = Wo + (size_t)j * 1024;
    float s = 0.0f;
#pragma unroll
    for (int i = 0; i < 4; ++i) s += wr[t + i * 256] * bv[t + i * 256];
#pragma unroll
    for (int o = 32; o > 0; o >>= 1) s += __shfl_down(s, o);
    if ((t & 63) == 0) ws4[t >> 6] = s;
    __syncthreads();
    if (t == 0) bvo[j] = ws4[0] + ws4[1] + ws4[2] + ws4[3] + bo[j];
}

__global__ __launch_bounds__(256)
void cast_act(const float* __restrict__ src, bf16_t* __restrict__ dst)
{
    const size_t i = ((size_t)blockIdx.x * 256 + threadIdx.x) * 4;
    const float4 f = *(const float4*)(src + i);
    bf16x4 h = {(bf16_t)f.x, (bf16_t)f.y, (bf16_t)f.z, (bf16_t)f.w};
    *(bf16x4*)(dst + i) = h;
}

__global__ __launch_bounds__(256)
void concat_bias(const float* __restrict__ a, const float* __restrict__ b,
                 float* __restrict__ dst)
{
    const int i = blockIdx.x * 256 + threadIdx.x;
    if (i < 1024) dst[i] = a[i];
    else if (i < 2048) dst[i] = b[i - 1024];
}

// ---------------------------------------------------------------------------
// One block per row: dual l2norm + sigmoid gate + exact top-80 (radix select
// on abs bits, stable lowest-index tie-break) + sparse write + visual concat.
// Scans are wave-level shfl_up (2 barriers/pass instead of 16).
// ---------------------------------------------------------------------------
__global__ __launch_bounds__(256)
void finalize_topk(float* __restrict__ AgF,      // OUT2: in Ag, out final
                   float* __restrict__ AlF,      // OUT3: in Al, out f2
                   const float* __restrict__ VIS,
                   float* __restrict__ O1)
{
    const int row = blockIdx.x, t = threadIdx.x;
    __shared__ int bins[256];
    __shared__ float wred[8];
    __shared__ int wsum[4];
    __shared__ int s_sel, s_kk;

    float* agp = AgF + (size_t)row * 1024 + t * 4;
    float* alp = AlF + (size_t)row * 1024 + t * 4;
    const float4 a4 = *(const float4*)agp;
    const float4 l4 = *(const float4*)alp;
    float av[4] = {a4.x, a4.y, a4.z, a4.w};
    float lv[4] = {l4.x, l4.y, l4.z, l4.w};
    float sa = 0.0f, sb = 0.0f;
#pragma unroll
    for (int j = 0; j < 4; ++j) { sa += av[j] * av[j]; sb += lv[j] * lv[j]; }
#pragma unroll
    for (int o = 32; o > 0; o >>= 1) {
        sa += __shfl_down(sa, o);
        sb += __shfl_down(sb, o);
    }
    if ((t & 63) == 0) { wred[t >> 6] = sa; wred[4 + (t >> 6)] = sb; }
    __syncthreads();
    const float sca = 1.0f / fmaxf(sqrtf(wred[0] + wred[1] + wred[2] + wred[3]), 1e-12f);
    const float scl = 1.0f / fmaxf(sqrtf(wred[4] + wred[5] + wred[6] + wred[7]), 1e-12f);

    float fv[4], f2v[4];
    unsigned ab[4];
#pragma unroll
    for (int j = 0; j < 4; ++j) {
        const float f2 = lv[j] * scl;
        const float f1 = av[j] * sca;
        const float fin = f2 / (1.0f + __expf(-f1));   // sigmoid(f1)*f2
        f2v[j] = f2; fv[j] = fin;
        ab[j] = __float_as_uint(fin) & 0x7fffffffu;
    }
    *(float4*)alp = make_float4(f2v[0], f2v[1], f2v[2], f2v[3]);
    *(float4*)agp = make_float4(fv[0], fv[1], fv[2], fv[3]);

    const float* vr = VIS + (size_t)row * 2048;
    float* o1r = O1 + (size_t)row * 3072;
    *(float4*)(o1r + t * 4)        = *(const float4*)(vr + t * 4);
    *(float4*)(o1r + 1024 + t * 4) = *(const float4*)(vr + 1024 + t * 4);

    // --- radix select: exact bits of the 80th-largest |fin| ---
    unsigned pref = 0u, msk = 0u;
    int kk = 80;
    for (int bp = 3; bp >= 0; --bp) {
        bins[t] = 0;
        __syncthreads();
#pragma unroll
        for (int j = 0; j < 4; ++j)
            if ((ab[j] & msk) == pref)
                atomicAdd(&bins[(ab[j] >> (bp * 8)) & 255], 1);
        __syncthreads();
        const int x = bins[t];
        int p = x;
#pragma unroll
        for (int o = 1; o < 64; o <<= 1) {
            const int y = __shfl_up(p, o);
            if ((t & 63) >= o) p += y;
        }
        if ((t & 63) == 63) wsum[t >> 6] = p;
        __syncthreads();
        const int tot = wsum[0] + wsum[1] + wsum[2] + wsum[3];
        int off = 0;
        if ((t >> 6) > 0) off += wsum[0];
        if ((t >> 6) > 1) off += wsum[1];
        if ((t >> 6) > 2) off += wsum[2];
        p += off;                              // inclusive prefix over 256
        const int Sme = tot - p + x;           // suffix sum incl. bin t
        const int Snx = tot - p;               // suffix sum from bin t+1
        if (Sme >= kk && Snx < kk) { s_sel = t; s_kk = kk - Snx; }
        __syncthreads();
        pref |= (unsigned)s_sel << (bp * 8);
        msk  |= 0xFFu << (bp * 8);
        kk = s_kk;
        __syncthreads();
    }

    // stable tie-break: keep first kk elements equal to threshold (index order)
    int ec = 0;
#pragma unroll
    for (int j = 0; j < 4; ++j) ec += (ab[j] == pref) ? 1 : 0;
    int pe = ec;
#pragma unroll
    for (int o = 1; o < 64; o <<= 1) {
        const int y = __shfl_up(pe, o);
        if ((t & 63) >= o) pe += y;
    }
    if ((t & 63) == 63) wsum[t >> 6] = pe;
    __syncthreads();
    int off2 = 0;
    if ((t >> 6) > 0) off2 += wsum[0];
    if ((t >> 6) > 1) off2 += wsum[1];
    if ((t >> 6) > 2) off2 += wsum[2];
    int excl = pe + off2 - ec;
#pragma unroll
    for (int j = 0; j < 4; ++j) {
        const bool eq = (ab[j] == pref);
        const bool kp = (ab[j] > pref) || (eq && (excl < kk));
        o1r[2048 + t * 4 + j] = kp ? fv[j] : 0.0f;
        if (eq) ++excl;
    }
}

// ---------------------------------------------------------------------------
extern "C" void kernel_launch(void* const* d_in, const int* in_sizes, int n_in,
                              void* d_out, int out_size, void* d_ws, size_t ws_size,
                              hipStream_t stream)
{
    const float* SG   = (const float*)d_in[0];
    const float* SL   = (const float*)d_in[1];
    const float* VIS  = (const float*)d_in[2];
    const float* Wgu1 = (const float*)d_in[3];
    const float* bgu1 = (const float*)d_in[4];
    const float* Wgu2 = (const float*)d_in[5];  const float* bgu2 = (const float*)d_in[6];
    const float* Wgd1 = (const float*)d_in[7];  const float* bgd1 = (const float*)d_in[8];
    const float* Wgd2 = (const float*)d_in[9];  const float* bgd2 = (const float*)d_in[10];
    const float* Wlu1 = (const float*)d_in[11]; const float* blu1 = (const float*)d_in[12];
    const float* Wlu2 = (const float*)d_in[13]; const float* blu2 = (const float*)d_in[14];
    const float* Wld1 = (const float*)d_in[15]; const float* bld1 = (const float*)d_in[16];
    const float* Wld2 = (const float*)d_in[17]; const float* bld2 = (const float*)d_in[18];
    const float* Wo   = (const float*)d_in[19]; const float* bo   = (const float*)d_in[20];
    const float* Win  = (const float*)d_in[21]; const float* bin_ = (const float*)d_in[22];
    const float* Wv = Win + (size_t)2 * 1024 * 1024;   // Win[2E:]
    const float* bv = bin_ + 2048;

    float* OUT1 = (float*)d_out;                         // B x 3072
    float* OUT2 = OUT1 + (size_t)16384 * 3072;           // B x 1024 (final)
    float* OUT3 = OUT2 + (size_t)16384 * 1024;           // B x 1024 (f2)

    // ws: bf16 weights (8 MLP + Wo + composed Wvo) + biases  (~21 MB)
    char* ws = (char*)d_ws;
    bf16_t* Wbf  = (bf16_t*)ws;                          // 8 x 1M (MLP)
    bf16_t* Wo_b = Wbf + (size_t)8 * 1048576;            // [16,18) MB
    bf16_t* Wvo  = Wbf + (size_t)9 * 1048576;            // [18,20) MB
    float*  bb   = (float*)(ws + 20971520);              // 4096 f32
    float*  bvo  = bb + 4096;                            // 1024 f32

    // scratch inside d_out (320 MiB), lifetime-checked:
    //   X  [0,32)M  Y [32,64)M : cast sg/sl, rewritten by D3 as sg'/sl'
    //   Ug [64,96)M Ul [96,128)M : gate pre-acts (D2 out, D3 in)
    //   H1g[128,192)M H1l[192,256)M : D1 out, D2/D3 in (dead after D3)
    //   WvT lives in H1g's slot before D1 runs.
    //   D45 writes OUT2/OUT3 [192,320)M; finalize overwrites [0,192)M (OUT1).
    bf16_t* X   = (bf16_t*)d_out;
    bf16_t* Y   = X + (size_t)16384 * 1024;
    bf16_t* Ug  = (bf16_t*)((char*)d_out + 67108864);
    bf16_t* Ul  = (bf16_t*)((char*)d_out + 100663296);
    bf16_t* H1g = (bf16_t*)((char*)d_out + 134217728);
    bf16_t* H1l = (bf16_t*)((char*)d_out + 201326592);
    bf16_t* WvT = H1g;                                   // transient, pre-D1

    WSrcs srcs;
    srcs.p[0] = Wgu1; srcs.p[1] = Wgd1; srcs.p[2] = Wlu1; srcs.p[3] = Wld1;
    srcs.p[4] = Wgu2; srcs.p[5] = Wgd2; srcs.p[6] = Wlu2; srcs.p[7] = Wld2;
    srcs.p[8] = Wo;

    cast_weights<<<9216, 256, 0, stream>>>(srcs, Wbf);
    transpose_cast<<<dim3(16, 16), 256, 0, stream>>>(Wv, WvT);
    concat_bias<<<8, 256, 0, stream>>>(bgu1, bgd1, bb);
    concat_bias<<<8, 256, 0, stream>>>(blu1, bld1, bb + 2048);
    bias_compose<<<1024, 256, 0, stream>>>(Wo, bv, bo, bvo);
    cast_act<<<16384, 256, 0, stream>>>(SG, X);
    cast_act<<<16384, 256, 0, stream>>>(SL, Y);

    // Wvo[n][k] = sum_m Wo[n][m] * Wv[m][k]  (= Wo @ Wv), bf16
    gemm_small_bt<<<dim3(8, 8), 256, 0, stream>>>(Wo_b, 1024, WvT, Wvo, 1024, 1024);

    bf16_t* Wg1   = Wbf;                                 // [Wgu1;Wgd1] 2048x1024
    bf16_t* Wl1   = Wbf + (size_t)2 * 1048576;           // [Wlu1;Wld1]
    bf16_t* Wgu2b = Wbf + (size_t)4 * 1048576;
    bf16_t* Wgd2b = Wbf + (size_t)5 * 1048576;
    bf16_t* Wlu2b = Wbf + (size_t)6 * 1048576;
    bf16_t* Wld2b = Wbf + (size_t)7 * 1048576;

    // D1: h1 = relu([X;Y] @ [W?u1;W?d1]^T + b), per-half weights. N=2048.
    gemm256<0><<<1024, 512, 0, stream>>>(X, Y, 1024, Wg1, Wl1, bb, bb + 2048,
                                         nullptr, nullptr, H1g, H1l, 2048, 1024, 8, 64, 16);
    // D2: U = h1[:, :1024] @ W?u2^T + b  (gate pre-act)
    gemm256<1><<<512, 512, 0, stream>>>(H1g, H1l, 2048, Wgu2b, Wlu2b, bgu2, blu2,
                                        nullptr, nullptr, Ug, Ul, 1024, 1024, 4, 64, 8);
    // D3: s? = sigmoid(U) * (h1[:, 1024:] @ W?d2^T + b)  -> X, Y
    gemm256<2><<<512, 512, 0, stream>>>(H1g + 1024, H1l + 1024, 2048, Wgd2b, Wld2b,
                                        bgd2, bld2, Ug, Ul, X, Y, 1024, 1024, 4, 64, 8);
    // D45: pre-norm attn_out = [sg;sl] @ Wvo^T + bvo -> OUT2/OUT3 (M=32768)
    gemm256<3><<<512, 512, 0, stream>>>(X, X, 1024, Wvo, Wvo, bvo, bvo,
                                        nullptr, nullptr, OUT2, OUT2, 1024, 1024, 4, 128, 4);

    finalize_topk<<<16384, 256, 0, stream>>>(OUT2, OUT3, VIS, OUT1);
}

// Round 6
// 637.023 us; speedup vs baseline: 2.3626x; 1.0578x over previous
//
#include <hip/hip_runtime.h>

typedef __bf16 bf16_t;
typedef __bf16 bf16x4 __attribute__((ext_vector_type(4)));
typedef __bf16 bf16x8 __attribute__((ext_vector_type(8)));
typedef float f32x4 __attribute__((ext_vector_type(4)));

#define GLL16(gp, lp) __builtin_amdgcn_global_load_lds( \
    (__attribute__((address_space(1))) void*)(gp),      \
    (__attribute__((address_space(3))) void*)(lp), 16, 0, 0)

// ---------------------------------------------------------------------------
// 256x256-tile GEMM, BK=32, 4-deep LDS ring, counted vmcnt (T3+T4).
//   C[half][M,N] = epi(A[half][M,K] @ W[half][N,K]^T + bias[half])
// 512 threads = 8 waves (2M x 4N); per-wave output 128x64. K=1024 (NT=32).
// LDS 128 KiB: ring of 4 steps x (A 256x32 + B 256x32) bf16.
// Swizzle: 16B-granule XOR by row&3 (4 granules/row), applied on global
// source (staging) and ds_read (both-sides involution) -> uniform banks.
// Pipeline: step s stages step s+3 (4 global_load_lds/thread, A+B);
// at step end waits vmcnt(8) -> only 3-step-old loads block (~5 phases of
// slack), the 8 newer loads remain in flight across barriers (never drain
// to 0 in the main loop; tail peels vmcnt(4)/vmcnt(0)).
// Per phase: [stage][ds_read] barrier; lgkmcnt(0); sched_barrier; setprio(1);
// 16 independent MFMA; setprio(0); [vmcnt]; barrier.  (r3-verified skeleton)
// Epilogue n-innermost (full-line write combining).
// XCD window remap: XCD owns nbyH/8 byh rows x all c, in 8x4 windows.
// EPI: 0 relu->bf16, 1 bias->bf16, 2 sigmoid(U)*v->bf16, 3 bias->f32
// ---------------------------------------------------------------------------
#define STAGE_STEP(NXT) do {                                                 \
    GLL16(asrc0 + koff, &As[(NXT) * 8192 + t * 8]);                          \
    GLL16(asrc1 + koff, &As[(NXT) * 8192 + (t + 512) * 8]);                  \
    GLL16(bsrc0 + koff, &Bs[(NXT) * 8192 + t * 8]);                          \
    GLL16(bsrc1 + koff, &Bs[(NXT) * 8192 + (t + 512) * 8]);                  \
    koff += 32; } while (0)

#define VM8 asm volatile("s_waitcnt vmcnt(8)" ::: "memory")
#define VM4 asm volatile("s_waitcnt vmcnt(4)" ::: "memory")
#define VM0 asm volatile("s_waitcnt vmcnt(0)" ::: "memory")
#define VMN ((void)0)

#define STEP(CUR, NXT, DOSTG, VMW) do {                                      \
    /* phase A: stage step s+3; read bq + af(m0-3); MFMA m0-3 */             \
    if (DOSTG) { STAGE_STEP(NXT); }                                          \
    _Pragma("unroll") for (int n = 0; n < 4; ++n)                            \
        bq[n] = *(const bf16x8*)(bT + (CUR) * 8192 + n * 512);               \
    _Pragma("unroll") for (int m = 0; m < 4; ++m)                            \
        af[m] = *(const bf16x8*)(aT + (CUR) * 8192 + m * 512);               \
    __builtin_amdgcn_s_barrier();                                            \
    asm volatile("s_waitcnt lgkmcnt(0)" ::: "memory");                       \
    __builtin_amdgcn_sched_barrier(0);                                       \
    __builtin_amdgcn_s_setprio(1);                                           \
    _Pragma("unroll") for (int m = 0; m < 4; ++m)                            \
    _Pragma("unroll") for (int n = 0; n < 4; ++n)                            \
        acc[m][n] = __builtin_amdgcn_mfma_f32_16x16x32_bf16(                 \
            af[m], bq[n], acc[m][n], 0, 0, 0);                               \
    __builtin_amdgcn_s_setprio(0);                                           \
    __builtin_amdgcn_s_barrier();                                            \
    /* phase B: read af(m4-7); MFMA m4-7; counted vmcnt; flip */             \
    _Pragma("unroll") for (int m = 0; m < 4; ++m)                            \
        af[m] = *(const bf16x8*)(aT + (CUR) * 8192 + (m + 4) * 512);         \
    __builtin_amdgcn_s_barrier();                                            \
    asm volatile("s_waitcnt lgkmcnt(0)" ::: "memory");                       \
    __builtin_amdgcn_sched_barrier(0);                                       \
    __builtin_amdgcn_s_setprio(1);                                           \
    _Pragma("unroll") for (int m = 0; m < 4; ++m)                            \
    _Pragma("unroll") for (int n = 0; n < 4; ++n)                            \
        acc[m + 4][n] = __builtin_amdgcn_mfma_f32_16x16x32_bf16(             \
            af[m], bq[n], acc[m + 4][n], 0, 0, 0);                           \
    __builtin_amdgcn_s_setprio(0);                                           \
    VMW;                                                                     \
    __builtin_amdgcn_s_barrier();                                            \
    } while (0)

template<int EPI>
__global__ __launch_bounds__(512, 2)
void gemm256(const bf16_t* __restrict__ A0, const bf16_t* __restrict__ A1, int lda,
             const bf16_t* __restrict__ W0, const bf16_t* __restrict__ W1,
             const float* __restrict__ bias0, const float* __restrict__ bias1,
             const bf16_t* __restrict__ U0, const bf16_t* __restrict__ U1,
             void* __restrict__ C0v, void* __restrict__ C1v, int ldc,
             int K, int nbx, int nbyH, int ctot)
{
    __shared__ bf16_t As[4 * 8192];           // 4 ring steps x 256x32
    __shared__ bf16_t Bs[4 * 8192];

    const int t = threadIdx.x;
    const int w = t >> 6, l = t & 63;
    const int wr = w >> 2, wc = w & 3;        // 2 x 4 wave grid
    const int ro = l & 15, hi = l >> 4;
    const int g0 = hi ^ (ro & 3);             // swizzled granule (4/row)

    // XCD-window remap (gridDim%8==0, nbyH%8==0, ctot%4==0):
    const int xcd   = blockIdx.x & 7;
    const int local = blockIdx.x >> 3;
    const int wpb   = ctot >> 2;              // c-windows per byh stripe
    const int win   = local >> 5;
    const int r5    = local & 31;
    const int strp  = win / wpb;
    const int wcn   = win - strp * wpb;
    const int byh   = xcd * (nbyH >> 3) + strp * 8 + (r5 >> 2);
    const int c     = wcn * 4 + (r5 & 3);
    const int sel   = (c >= nbx) ? 1 : 0;
    const int bx    = c - sel * nbx;

    const bf16_t* A    = sel ? A1 : A0;
    const bf16_t* W    = sel ? W1 : W0;
    const float*  bias = sel ? bias1 : bias0;
    const bf16_t* Up   = sel ? U1 : U0;
    void*         Cp   = sel ? C1v : C0v;

    const bf16_t* Ab = A + (size_t)byh * 256 * lda;
    const bf16_t* Wb = W + (size_t)bx * 256 * K;

    // staging: thread t owns granules t and t+512 of each 256x32 step-tile;
    // granule g: row = g>>2, src col-granule = (g&3) ^ (row&3)  (inverse swz)
    const int srow = t >> 2;
    const int scg  = (t & 3) ^ (srow & 3);
    const bf16_t* asrc0 = Ab + (size_t)srow * lda + scg * 8;
    const bf16_t* asrc1 = asrc0 + (size_t)128 * lda;
    const bf16_t* bsrc0 = Wb + (size_t)srow * K + scg * 8;
    const bf16_t* bsrc1 = bsrc0 + (size_t)128 * K;
    int koff = 0;

    const bf16_t* aT = As + (wr * 128 + ro) * 32 + g0 * 8;
    const bf16_t* bT = Bs + (wc * 64 + ro) * 32 + g0 * 8;

    f32x4 acc[8][4] = {};
    bf16x8 bq[4];
    bf16x8 af[4];

    // prologue: stage steps 0,1,2; wait step 0 (counted), keep 8 in flight
    STAGE_STEP(0);
    STAGE_STEP(1);
    STAGE_STEP(2);
    VM8;
    __builtin_amdgcn_s_barrier();

    // NT = 32 steps (K must be 1024). Main: 28 steps; tail: 4 peeled.
#pragma unroll 1
    for (int it = 0; it < 7; ++it) {
        STEP(0, 3, true, VM8);
        STEP(1, 0, true, VM8);
        STEP(2, 1, true, VM8);
        STEP(3, 2, true, VM8);
    }
    STEP(0, 3, true, VM8);                    // s=28, stages step 31
    STEP(1, 0, false, VM4);                   // s=29
    STEP(2, 1, false, VM0);                   // s=30
    STEP(3, 2, false, VMN);                   // s=31

    // epilogue: C/D frag layout col=lane&15, row=(lane>>4)*4+j  [guide m89]
    const int rbase = byh * 256 + wr * 128 + (hi << 2);
    const int cbase = bx * 256 + wc * 64 + ro;
    float bc[4];
#pragma unroll
    for (int n = 0; n < 4; ++n) bc[n] = bias[cbase + n * 16];
#pragma unroll
    for (int m = 0; m < 8; ++m) {
#pragma unroll
        for (int j = 0; j < 4; ++j) {
            const int row = rbase + m * 16 + j;
            const size_t off = (size_t)row * ldc + cbase;
#pragma unroll
            for (int n = 0; n < 4; ++n) {
                float v = acc[m][n][j] + bc[n];
                if (EPI == 0) v = fmaxf(v, 0.0f);
                if (EPI == 2) {
                    const float u = (float)Up[off + n * 16];
                    v *= 1.0f / (1.0f + __expf(-u));
                }
                if (EPI == 3) ((float*)Cp)[off + n * 16] = v;
                else          ((bf16_t*)Cp)[off + n * 16] = (bf16_t)v;
            }
        }
    }
}

// ---------------------------------------------------------------------------
// Small 128x128-tile GEMM (r1 structure) for the Wo@Wv weight compose.
// C[M,N](bf16) = A[M,K] @ W[N,K]^T, no bias. Grid (N/128, M/128).
// ---------------------------------------------------------------------------
__global__ __launch_bounds__(256, 2)
void gemm_small_bt(const bf16_t* __restrict__ A, int lda,
                   const bf16_t* __restrict__ W,
                   bf16_t* __restrict__ C, int ldc, int K)
{
    __shared__ bf16_t As[128 * 64];
    __shared__ bf16_t Bs[128 * 64];
    const int t = threadIdx.x;
    const int w = t >> 6, l = t & 63;
    const int wr = w >> 1, wc = w & 1;

    const bf16_t* Ab = A + (size_t)blockIdx.y * 128 * lda;
    const bf16_t* Wb = W + (size_t)blockIdx.x * 128 * K;

    const bf16_t* asrc[4];
    const bf16_t* bsrc[4];
#pragma unroll
    for (int r = 0; r < 4; ++r) {
        const int seg = r * 256 + t;
        asrc[r] = Ab + (size_t)(seg >> 3) * lda + (seg & 7) * 8;
        bsrc[r] = Wb + (size_t)(seg >> 3) * K   + (seg & 7) * 8;
    }

    f32x4 acc[4][4] = {};

    for (int kt = 0; kt < K; kt += 64) {
#pragma unroll
        for (int r = 0; r < 4; ++r) {
            GLL16(asrc[r], As + (r * 256 + w * 64) * 8);
            GLL16(bsrc[r], Bs + (r * 256 + w * 64) * 8);
            asrc[r] += 64;
            bsrc[r] += 64;
        }
        __syncthreads();
#pragma unroll
        for (int kk = 0; kk < 2; ++kk) {
            const int ro = l & 15;
            const int ko = kk * 32 + (l >> 4) * 8;
            bf16x8 af[4], bq[4];
#pragma unroll
            for (int m = 0; m < 4; ++m)
                af[m] = *(const bf16x8*)(As + (wr * 64 + m * 16 + ro) * 64 + ko);
#pragma unroll
            for (int n = 0; n < 4; ++n)
                bq[n] = *(const bf16x8*)(Bs + (wc * 64 + n * 16 + ro) * 64 + ko);
#pragma unroll
            for (int m = 0; m < 4; ++m)
#pragma unroll
                for (int n = 0; n < 4; ++n)
                    acc[m][n] = __builtin_amdgcn_mfma_f32_16x16x32_bf16(
                        af[m], bq[n], acc[m][n], 0, 0, 0);
        }
        __syncthreads();
    }

    const int rbase = blockIdx.y * 128 + wr * 64 + ((l >> 4) << 2);
    const int cbase = blockIdx.x * 128 + wc * 64 + (l & 15);
#pragma unroll
    for (int m = 0; m < 4; ++m)
#pragma unroll
        for (int j = 0; j < 4; ++j) {
            const int row = rbase + m * 16 + j;
#pragma unroll
            for (int n = 0; n < 4; ++n)
                C[(size_t)row * ldc + cbase + n * 16] = (bf16_t)acc[m][n][j];
        }
}

// ---------------------------------------------------------------------------
struct WSrcs { const float* p[9]; };

__global__ __launch_bounds__(256)
void cast_weights(WSrcs srcs, bf16_t* __restrict__ dst)
{
    const int region = blockIdx.x >> 10;
    const float* src = srcs.p[region];
    const size_t base = (size_t)(blockIdx.x & 1023) * 1024 + threadIdx.x * 4;
    const float4 f = *(const float4*)(src + base);
    bf16x4 h = {(bf16_t)f.x, (bf16_t)f.y, (bf16_t)f.z, (bf16_t)f.w};
    *(bf16x4*)(dst + ((size_t)region << 20) + base) = h;
}

// Wv[m][k] (f32) -> WvT[k][m] (bf16); 64x64 tiles via padded LDS.
__global__ __launch_bounds__(256)
void transpose_cast(const float* __restrict__ src, bf16_t* __restrict__ dst)
{
    __shared__ bf16_t tile[64][65];
    const int bm = blockIdx.y * 64, bk = blockIdx.x * 64;
    const int t = threadIdx.x;
#pragma unroll
    for (int s = 0; s < 4; ++s) {
        const int r = s * 16 + (t >> 4);
        const int c = (t & 15) * 4;
        const float4 f = *(const float4*)(src + (size_t)(bm + r) * 1024 + bk + c);
        tile[r][c] = (bf16_t)f.x; tile[r][c + 1] = (bf16_t)f.y;
        tile[r][c + 2] = (bf16_t)f.z; tile[r][c + 3] = (bf16_t)f.w;
    }
    __syncthreads();
#pragma unroll
    for (int s = 0; s < 4; ++s) {
        const int k = s * 16 + (t >> 4);
        const int m = (t & 15) * 4;
        bf16x4 v = {tile[m][k], tile[m + 1][k], tile[m + 2][k], tile[m + 3][k]};
        *(bf16x4*)(dst + (size_t)(bk + k) * 1024 + bm + m) = v;
    }
}

// bvo[j] = dot(Wo[j,:], bv) + bo[j]
__global__ __launch_bounds__(256)
void bias_compose(const float* __restrict__ Wo, const float* __restrict__ bv,
                  const float* __restrict__ bo, float* __restrict__ bvo)
{
    const int j = blockIdx.x, t = threadIdx.x;
    __shared__ float ws4[4];
    const float* wr = Wo + (size_t)j * 1024;
    float s = 0.0f;
#pragma unroll
    for (int i = 0; i < 4; ++i) s += wr[t + i * 256] * bv[t + i * 256];
#pragma unroll
    for (int o = 32; o > 0; o >>= 1) s += __shfl_down(s, o);
    if ((t & 63) == 0) ws4[t >> 6] = s;
    __syncthreads();
    if (t == 0) bvo[j] = ws4[0] + ws4[1] + ws4[2] + ws4[3] + bo[j];
}

__global__ __launch_bounds__(256)
void cast_act(const float* __restrict__ src, bf16_t* __restrict__ dst)
{
    const size_t i = ((size_t)blockIdx.x * 256 + threadIdx.x) * 4;
    const float4 f = *(const float4*)(src + i);
    bf16x4 h = {(bf16_t)f.x, (bf16_t)f.y, (bf16_t)f.z, (bf16_t)f.w};
    *(bf16x4*)(dst + i) = h;
}

__global__ __launch_bounds__(256)
void concat_bias(const float* __restrict__ a, const float* __restrict__ b,
                 float* __restrict__ dst)
{
    const int i = blockIdx.x * 256 + threadIdx.x;
    if (i < 1024) dst[i] = a[i];
    else if (i < 2048) dst[i] = b[i - 1024];
}

// ---------------------------------------------------------------------------
// One block per row: dual l2norm + sigmoid gate + exact top-80 (radix select
// on abs bits, stable lowest-index tie-break) + sparse write + visual concat.
// Scans are wave-level shfl_up (2 barriers/pass instead of 16).
// ---------------------------------------------------------------------------
__global__ __launch_bounds__(256)
void finalize_topk(float* __restrict__ AgF,      // OUT2: in Ag, out final
                   float* __restrict__ AlF,      // OUT3: in Al, out f2
                   const float* __restrict__ VIS,
                   float* __restrict__ O1)
{
    const int row = blockIdx.x, t = threadIdx.x;
    __shared__ int bins[256];
    __shared__ float wred[8];
    __shared__ int wsum[4];
    __shared__ int s_sel, s_kk;

    float* agp = AgF + (size_t)row * 1024 + t * 4;
    float* alp = AlF + (size_t)row * 1024 + t * 4;
    const float4 a4 = *(const float4*)agp;
    const float4 l4 = *(const float4*)alp;
    float av[4] = {a4.x, a4.y, a4.z, a4.w};
    float lv[4] = {l4.x, l4.y, l4.z, l4.w};
    float sa = 0.0f, sb = 0.0f;
#pragma unroll
    for (int j = 0; j < 4; ++j) { sa += av[j] * av[j]; sb += lv[j] * lv[j]; }
#pragma unroll
    for (int o = 32; o > 0; o >>= 1) {
        sa += __shfl_down(sa, o);
        sb += __shfl_down(sb, o);
    }
    if ((t & 63) == 0) { wred[t >> 6] = sa; wred[4 + (t >> 6)] = sb; }
    __syncthreads();
    const float sca = 1.0f / fmaxf(sqrtf(wred[0] + wred[1] + wred[2] + wred[3]), 1e-12f);
    const float scl = 1.0f / fmaxf(sqrtf(wred[4] + wred[5] + wred[6] + wred[7]), 1e-12f);

    float fv[4], f2v[4];
    unsigned ab[4];
#pragma unroll
    for (int j = 0; j < 4; ++j) {
        const float f2 = lv[j] * scl;
        const float f1 = av[j] * sca;
        const float fin = f2 / (1.0f + __expf(-f1));   // sigmoid(f1)*f2
        f2v[j] = f2; fv[j] = fin;
        ab[j] = __float_as_uint(fin) & 0x7fffffffu;
    }
    *(float4*)alp = make_float4(f2v[0], f2v[1], f2v[2], f2v[3]);
    *(float4*)agp = make_float4(fv[0], fv[1], fv[2], fv[3]);

    const float* vr = VIS + (size_t)row * 2048;
    float* o1r = O1 + (size_t)row * 3072;
    *(float4*)(o1r + t * 4)        = *(const float4*)(vr + t * 4);
    *(float4*)(o1r + 1024 + t * 4) = *(const float4*)(vr + 1024 + t * 4);

    // --- radix select: exact bits of the 80th-largest |fin| ---
    unsigned pref = 0u, msk = 0u;
    int kk = 80;
    for (int bp = 3; bp >= 0; --bp) {
        bins[t] = 0;
        __syncthreads();
#pragma unroll
        for (int j = 0; j < 4; ++j)
            if ((ab[j] & msk) == pref)
                atomicAdd(&bins[(ab[j] >> (bp * 8)) & 255], 1);
        __syncthreads();
        const int x = bins[t];
        int p = x;
#pragma unroll
        for (int o = 1; o < 64; o <<= 1) {
            const int y = __shfl_up(p, o);
            if ((t & 63) >= o) p += y;
        }
        if ((t & 63) == 63) wsum[t >> 6] = p;
        __syncthreads();
        const int tot = wsum[0] + wsum[1] + wsum[2] + wsum[3];
        int off = 0;
        if ((t >> 6) > 0) off += wsum[0];
        if ((t >> 6) > 1) off += wsum[1];
        if ((t >> 6) > 2) off += wsum[2];
        p += off;                              // inclusive prefix over 256
        const int Sme = tot - p + x;           // suffix sum incl. bin t
        const int Snx = tot - p;               // suffix sum from bin t+1
        if (Sme >= kk && Snx < kk) { s_sel = t; s_kk = kk - Snx; }
        __syncthreads();
        pref |= (unsigned)s_sel << (bp * 8);
        msk  |= 0xFFu << (bp * 8);
        kk = s_kk;
        __syncthreads();
    }

    // stable tie-break: keep first kk elements equal to threshold (index order)
    int ec = 0;
#pragma unroll
    for (int j = 0; j < 4; ++j) ec += (ab[j] == pref) ? 1 : 0;
    int pe = ec;
#pragma unroll
    for (int o = 1; o < 64; o <<= 1) {
        const int y = __shfl_up(pe, o);
        if ((t & 63) >= o) pe += y;
    }
    if ((t & 63) == 63) wsum[t >> 6] = pe;
    __syncthreads();
    int off2 = 0;
    if ((t >> 6) > 0) off2 += wsum[0];
    if ((t >> 6) > 1) off2 += wsum[1];
    if ((t >> 6) > 2) off2 += wsum[2];
    int excl = pe + off2 - ec;
#pragma unroll
    for (int j = 0; j < 4; ++j) {
        const bool eq = (ab[j] == pref);
        const bool kp = (ab[j] > pref) || (eq && (excl < kk));
        o1r[2048 + t * 4 + j] = kp ? fv[j] : 0.0f;
        if (eq) ++excl;
    }
}

// ---------------------------------------------------------------------------
extern "C" void kernel_launch(void* const* d_in, const int* in_sizes, int n_in,
                              void* d_out, int out_size, void* d_ws, size_t ws_size,
                              hipStream_t stream)
{
    const float* SG   = (const float*)d_in[0];
    const float* SL   = (const float*)d_in[1];
    const float* VIS  = (const float*)d_in[2];
    const float* Wgu1 = (const float*)d_in[3];
    const float* bgu1 = (const float*)d_in[4];
    const float* Wgu2 = (const float*)d_in[5];  const float* bgu2 = (const float*)d_in[6];
    const float* Wgd1 = (const float*)d_in[7];  const float* bgd1 = (const float*)d_in[8];
    const float* Wgd2 = (const float*)d_in[9];  const float* bgd2 = (const float*)d_in[10];
    const float* Wlu1 = (const float*)d_in[11]; const float* blu1 = (const float*)d_in[12];
    const float* Wlu2 = (const float*)d_in[13]; const float* blu2 = (const float*)d_in[14];
    const float* Wld1 = (const float*)d_in[15]; const float* bld1 = (const float*)d_in[16];
    const float* Wld2 = (const float*)d_in[17]; const float* bld2 = (const float*)d_in[18];
    const float* Wo   = (const float*)d_in[19]; const float* bo   = (const float*)d_in[20];
    const float* Win  = (const float*)d_in[21]; const float* bin_ = (const float*)d_in[22];
    const float* Wv = Win + (size_t)2 * 1024 * 1024;   // Win[2E:]
    const float* bv = bin_ + 2048;

    float* OUT1 = (float*)d_out;                         // B x 3072
    float* OUT2 = OUT1 + (size_t)16384 * 3072;           // B x 1024 (final)
    float* OUT3 = OUT2 + (size_t)16384 * 1024;           // B x 1024 (f2)

    // ws: bf16 weights (8 MLP + Wo + composed Wvo) + biases  (~21 MB)
    char* ws = (char*)d_ws;
    bf16_t* Wbf  = (bf16_t*)ws;                          // 8 x 1M (MLP)
    bf16_t* Wo_b = Wbf + (size_t)8 * 1048576;            // [16,18) MB
    bf16_t* Wvo  = Wbf + (size_t)9 * 1048576;            // [18,20) MB
    float*  bb   = (float*)(ws + 20971520);              // 4096 f32
    float*  bvo  = bb + 4096;                            // 1024 f32

    // scratch inside d_out (320 MiB), lifetime-checked (see r2/r5 notes)
    bf16_t* X   = (bf16_t*)d_out;
    bf16_t* Y   = X + (size_t)16384 * 1024;
    bf16_t* Ug  = (bf16_t*)((char*)d_out + 67108864);
    bf16_t* Ul  = (bf16_t*)((char*)d_out + 100663296);
    bf16_t* H1g = (bf16_t*)((char*)d_out + 134217728);
    bf16_t* H1l = (bf16_t*)((char*)d_out + 201326592);
    bf16_t* WvT = H1g;                                   // transient, pre-D1

    WSrcs srcs;
    srcs.p[0] = Wgu1; srcs.p[1] = Wgd1; srcs.p[2] = Wlu1; srcs.p[3] = Wld1;
    srcs.p[4] = Wgu2; srcs.p[5] = Wgd2; srcs.p[6] = Wlu2; srcs.p[7] = Wld2;
    srcs.p[8] = Wo;

    cast_weights<<<9216, 256, 0, stream>>>(srcs, Wbf);
    transpose_cast<<<dim3(16, 16), 256, 0, stream>>>(Wv, WvT);
    concat_bias<<<8, 256, 0, stream>>>(bgu1, bgd1, bb);
    concat_bias<<<8, 256, 0, stream>>>(blu1, bld1, bb + 2048);
    bias_compose<<<1024, 256, 0, stream>>>(Wo, bv, bo, bvo);
    cast_act<<<16384, 256, 0, stream>>>(SG, X);
    cast_act<<<16384, 256, 0, stream>>>(SL, Y);

    // Wvo[n][k] = sum_m Wo[n][m] * Wv[m][k]  (= Wo @ Wv), bf16
    gemm_small_bt<<<dim3(8, 8), 256, 0, stream>>>(Wo_b, 1024, WvT, Wvo, 1024, 1024);

    bf16_t* Wg1   = Wbf;                                 // [Wgu1;Wgd1] 2048x1024
    bf16_t* Wl1   = Wbf + (size_t)2 * 1048576;           // [Wlu1;Wld1]
    bf16_t* Wgu2b = Wbf + (size_t)4 * 1048576;
    bf16_t* Wgd2b = Wbf + (size_t)5 * 1048576;
    bf16_t* Wlu2b = Wbf + (size_t)6 * 1048576;
    bf16_t* Wld2b = Wbf + (size_t)7 * 1048576;

    // D1: h1 = relu([X;Y] @ [W?u1;W?d1]^T + b), per-half weights. N=2048.
    gemm256<0><<<1024, 512, 0, stream>>>(X, Y, 1024, Wg1, Wl1, bb, bb + 2048,
                                         nullptr, nullptr, H1g, H1l, 2048, 1024, 8, 64, 16);
    // D2: U = h1[:, :1024] @ W?u2^T + b  (gate pre-act)
    gemm256<1><<<512, 512, 0, stream>>>(H1g, H1l, 2048, Wgu2b, Wlu2b, bgu2, blu2,
                                        nullptr, nullptr, Ug, Ul, 1024, 1024, 4, 64, 8);
    // D3: s? = sigmoid(U) * (h1[:, 1024:] @ W?d2^T + b)  -> X, Y
    gemm256<2><<<512, 512, 0, stream>>>(H1g + 1024, H1l + 1024, 2048, Wgd2b, Wld2b,
                                        bgd2, bld2, Ug, Ul, X, Y, 1024, 1024, 4, 64, 8);
    // D45: pre-norm attn_out = [sg;sl] @ Wvo^T + bvo -> OUT2/OUT3 (M=32768)
    gemm256<3><<<512, 512, 0, stream>>>(X, X, 1024, Wvo, Wvo, bvo, bvo,
                                        nullptr, nullptr, OUT2, OUT2, 1024, 1024, 4, 128, 4);

    finalize_topk<<<16384, 256, 0, stream>>>(OUT2, OUT3, VIS, OUT1);
}